// Round 1
// baseline (39423.572 us; speedup 1.0000x reference)
//
#include <hip/hip_runtime.h>
#include <cmath>

#define NWG 256
#define NTHR 256

// Problem constants
static constexpr int kV = 32000;
static constexpr int kS = 1024;
static constexpr int kT = 512;

struct SeqParams {
  const int* x; const int* y;
  const float* emb;
  const float* eWih0; const float* eWhh0; const float* eb0;
  const float* eWih1; const float* eWhh1; const float* eb1;
  const float* efcW;  const float* efcb;
  const float* dWih0; const float* dWhh0; const float* db0;
  const float* dWih1; const float* dWhh1; const float* db1;
  const float* dfcW;  const float* dfcb;
  float* out;
  float* P0;      // [1024][2048] staging (ws or d_out fallback)
  float* st;      // small state area in ws
  unsigned* arrive;  // NWG slots, stride 32 uints (128B apart)
  unsigned* go;      // release flag
};

__device__ __forceinline__ float sigmf(float v) { return 1.0f / (1.0f + expf(-v)); }

// Contention-free grid barrier: workers release-publish to private slots,
// WG0 threads poll all slots in parallel, then publish `go`.
// __threadfence() (agent scope: wbL2 + inv) gives cross-XCD visibility of
// plain state loads/stores around the barrier.
__device__ void grid_barrier(const SeqParams& p, unsigned gen) {
  __syncthreads();
  if (blockIdx.x == 0) {
    const int tid = threadIdx.x;
    if (tid > 0) {
      while (__hip_atomic_load(&p.arrive[tid * 32], __ATOMIC_RELAXED,
                               __HIP_MEMORY_SCOPE_AGENT) < gen)
        __builtin_amdgcn_s_sleep(1);
    }
    __syncthreads();
    if (tid == 0) {
      __threadfence();
      __hip_atomic_store(p.go, gen, __ATOMIC_RELAXED, __HIP_MEMORY_SCOPE_AGENT);
    }
    __syncthreads();
  } else {
    if (threadIdx.x == 0) {
      __threadfence();  // flush this WG's state writes to L3
      __hip_atomic_store(&p.arrive[blockIdx.x * 32], gen, __ATOMIC_RELAXED,
                         __HIP_MEMORY_SCOPE_AGENT);
      while (__hip_atomic_load(p.go, __ATOMIC_RELAXED,
                               __HIP_MEMORY_SCOPE_AGENT) < gen)
        __builtin_amdgcn_s_sleep(1);
      __threadfence();  // invalidate stale lines before reading fresh state
    }
    __syncthreads();
  }
}

__global__ __launch_bounds__(NTHR) void seq2seq_kernel(SeqParams p) {
  __shared__ __align__(16) float lds_em[8192];  // 32KB: P0 emb staging
  __shared__ float lds_g[16];
  __shared__ float lds_rv[4];
  __shared__ int   lds_ri[4];
  __shared__ float lds_tok;

  const int w = blockIdx.x;
  const int tid = threadIdx.x;
  unsigned gen = 0;

  // state layout in ws (floats)
  float* H0e = p.st;              // [2][512]
  float* C0e = p.st + 1024;       // [512]
  float* H1e = p.st + 1536;       // [2][512]
  float* C1e = p.st + 2560;       // [512]
  float* H0d = p.st + 3072;       // [2][512]
  float* C0d = p.st + 4096;       // [512]
  float* H1d = p.st + 4608;       // [2][512]
  float* C1d = p.st + 5632;       // [512]
  float* candv = p.st + 6144;     // [256]
  int*   candi = reinterpret_cast<int*>(p.st + 6400);  // [256]

  // ================= Phase 0: P0 = emb[x] @ Wih0^T + b0 ; init enc state ===
  {
    if (w == 0) {
      for (int i = tid; i < 512; i += NTHR) {
        H0e[i] = 0.f; C0e[i] = 0.f; H1e[i] = 0.f; C1e[i] = 0.f;
      }
    }
    const int t0  = (w & 31) * 32;         // 32 t's per block
    const int row = (w >> 5) * 256 + tid;  // 8 row-slices of 256
    float4* emv = reinterpret_cast<float4*>(lds_em);
    for (int idx = tid; idx < 32 * 64; idx += NTHR) {
      const int tl = idx >> 6, kq = idx & 63;
      const int tk = p.x[t0 + tl];
      emv[idx] = reinterpret_cast<const float4*>(p.emb)[(size_t)tk * 64 + kq];
    }
    __syncthreads();
    float acc[32];
    const float b = p.eb0[row];
#pragma unroll
    for (int t = 0; t < 32; ++t) acc[t] = b;
    for (int kc = 0; kc < 4; ++kc) {
      float4 wv[16];
      const float4* wr =
          reinterpret_cast<const float4*>(p.eWih0 + (size_t)row * 256) + kc * 16;
#pragma unroll
      for (int i = 0; i < 16; ++i) wv[i] = wr[i];
#pragma unroll
      for (int t = 0; t < 32; ++t) {
        const float4* ev =
            reinterpret_cast<const float4*>(lds_em + t * 256) + kc * 16;
        float a = acc[t];
#pragma unroll
        for (int i = 0; i < 16; ++i) {
          const float4 e = ev[i];
          a += wv[i].x * e.x + wv[i].y * e.y + wv[i].z * e.z + wv[i].w * e.w;
        }
        acc[t] = a;
      }
    }
#pragma unroll
    for (int t = 0; t < 32; ++t) p.P0[(size_t)(t0 + t) * 2048 + row] = acc[t];
  }
  grid_barrier(p, ++gen);

  // ================= Encoder: pipelined L0(t=ph) || L1(t=ph-1) =============
  for (int ph = 0; ph <= kS; ++ph) {
    if (w < 128) {
      if (ph < kS) {  // L0 step t=ph: WGs 0..127 own 4 units each
        const int g = tid >> 4, l = tid & 15;  // 16 groups x 16 lanes
        const int u = w * 4 + (g >> 2);
        const int row = (g & 3) * 512 + u;     // gate-major rows (i,f,g,o)
        const float* Wr = p.eWhh0 + (size_t)row * 512;
        const float* h0 = H0e + (ph & 1) * 512;
        float a = 0.f;
#pragma unroll
        for (int m = 0; m < 32; ++m) a += Wr[l + 16 * m] * h0[l + 16 * m];
        a += __shfl_down(a, 8, 16);
        a += __shfl_down(a, 4, 16);
        a += __shfl_down(a, 2, 16);
        a += __shfl_down(a, 1, 16);
        if (l == 0) lds_g[g] = a + p.P0[(size_t)ph * 2048 + row];
        __syncthreads();
        if (tid < 4) {
          const int uu = w * 4 + tid;
          const float gi = lds_g[tid * 4 + 0];
          const float gf = lds_g[tid * 4 + 1];
          const float gg = lds_g[tid * 4 + 2];
          const float go = lds_g[tid * 4 + 3];
          const float c  = C0e[uu];
          const float c2 = sigmf(gf) * c + sigmf(gi) * tanhf(gg);
          C0e[uu] = c2;
          H0e[((ph + 1) & 1) * 512 + uu] = sigmf(go) * tanhf(c2);
        }
      }
    } else {
      if (ph >= 1) {  // L1 step t=ph-1: WGs 128..255 own 4 units each
        const int g = tid >> 4, l = tid & 15;
        const int u = (w - 128) * 4 + (g >> 2);
        const int row = (g & 3) * 512 + u;
        const float* Wa = p.eWih1 + (size_t)row * 512;
        const float* Wb = p.eWhh1 + (size_t)row * 512;
        const float* h0 = H0e + (ph & 1) * 512;        // h0_t (written ph-1)
        const float* h1 = H1e + ((ph - 1) & 1) * 512;  // h1_{t-1}
        float a = 0.f;
#pragma unroll
        for (int m = 0; m < 32; ++m) a += Wa[l + 16 * m] * h0[l + 16 * m];
#pragma unroll
        for (int m = 0; m < 32; ++m) a += Wb[l + 16 * m] * h1[l + 16 * m];
        a += __shfl_down(a, 8, 16);
        a += __shfl_down(a, 4, 16);
        a += __shfl_down(a, 2, 16);
        a += __shfl_down(a, 1, 16);
        if (l == 0) lds_g[g] = a + p.eb1[row];
        __syncthreads();
        if (tid < 4) {
          const int uu = (w - 128) * 4 + tid;
          const float gi = lds_g[tid * 4 + 0];
          const float gf = lds_g[tid * 4 + 1];
          const float gg = lds_g[tid * 4 + 2];
          const float go = lds_g[tid * 4 + 3];
          const float c  = C1e[uu];
          const float c2 = sigmf(gf) * c + sigmf(gi) * tanhf(gg);
          C1e[uu] = c2;
          H1e[(ph & 1) * 512 + uu] = sigmf(go) * tanhf(c2);
        }
      }
    }
    grid_barrier(p, ++gen);
  }

  // ================= z = relu(efcW @ h1_final + efcb); init decoder ========
  {
    const int g = tid >> 5, l = tid & 31;
    if (g < 2) {
      const int u = w * 2 + g;
      const float* Wr = p.efcW + (size_t)u * 512;
      const float* h1 = H1e;  // final h1 lives in buffer 0 (S even)
      float a = 0.f;
#pragma unroll
      for (int m = 0; m < 16; ++m) a += Wr[l + 32 * m] * h1[l + 32 * m];
      a += __shfl_down(a, 16, 32);
      a += __shfl_down(a, 8, 32);
      a += __shfl_down(a, 4, 32);
      a += __shfl_down(a, 2, 32);
      a += __shfl_down(a, 1, 32);
      if (l == 0) {
        const float z = fmaxf(a + p.efcb[u], 0.f);
        H0d[u] = z; C0d[u] = z; H1d[u] = z; C1d[u] = z;
      }
    }
    grid_barrier(p, ++gen);
  }

  // ================= Decoder: 511 steps, 3 phases each ======================
  for (int t = 0; t < kT - 1; ++t) {
    // ---- D0: token reduce + layer-0 cell ----
    {
      if (t == 0) {
        if (tid == 0) lds_tok = (float)p.y[0];
      } else if (tid < 64) {
        float bv = -INFINITY; int bi = 0x7fffffff;
#pragma unroll
        for (int j = 0; j < 4; ++j) {
          const float v = candv[tid + j * 64];
          const int  ix = candi[tid + j * 64];
          if (v > bv || (v == bv && ix < bi)) { bv = v; bi = ix; }
        }
#pragma unroll
        for (int off = 32; off >= 1; off >>= 1) {
          const float ov = __shfl_down(bv, off);
          const int   oi = __shfl_down(bi, off);
          if (ov > bv || (ov == bv && oi < bi)) { bv = ov; bi = oi; }
        }
        if (tid == 0) lds_tok = (float)bi;
      }
      __syncthreads();
      const float tok = lds_tok;
      const int g = tid >> 5, l = tid & 31;  // 8 groups x 32 lanes
      const int u = w * 2 + (g >> 2);
      const int row = (g & 3) * 512 + u;
      const float* Wr = p.dWhh0 + (size_t)row * 512;
      const float* h0 = H0d + (t & 1) * 512;
      float a = 0.f;
#pragma unroll
      for (int m = 0; m < 16; ++m) a += Wr[l + 32 * m] * h0[l + 32 * m];
      a += __shfl_down(a, 16, 32);
      a += __shfl_down(a, 8, 32);
      a += __shfl_down(a, 4, 32);
      a += __shfl_down(a, 2, 32);
      a += __shfl_down(a, 1, 32);
      if (l == 0) lds_g[g] = a + p.dWih0[row] * tok + p.db0[row];
      __syncthreads();
      if (tid < 2) {
        const int uu = w * 2 + tid;
        const float gi = lds_g[tid * 4 + 0];
        const float gf = lds_g[tid * 4 + 1];
        const float gg = lds_g[tid * 4 + 2];
        const float go = lds_g[tid * 4 + 3];
        const float c  = C0d[uu];
        const float c2 = sigmf(gf) * c + sigmf(gi) * tanhf(gg);
        C0d[uu] = c2;
        H0d[((t + 1) & 1) * 512 + uu] = sigmf(go) * tanhf(c2);
      }
    }
    grid_barrier(p, ++gen);
    // ---- D1: layer-1 cell ----
    {
      const int g = tid >> 5, l = tid & 31;
      const int u = w * 2 + (g >> 2);
      const int row = (g & 3) * 512 + u;
      const float* Wa = p.dWih1 + (size_t)row * 512;
      const float* Wb = p.dWhh1 + (size_t)row * 512;
      const float* h0 = H0d + ((t + 1) & 1) * 512;
      const float* h1 = H1d + (t & 1) * 512;
      float a = 0.f;
#pragma unroll
      for (int m = 0; m < 16; ++m) a += Wa[l + 32 * m] * h0[l + 32 * m];
#pragma unroll
      for (int m = 0; m < 16; ++m) a += Wb[l + 32 * m] * h1[l + 32 * m];
      a += __shfl_down(a, 16, 32);
      a += __shfl_down(a, 8, 32);
      a += __shfl_down(a, 4, 32);
      a += __shfl_down(a, 2, 32);
      a += __shfl_down(a, 1, 32);
      if (l == 0) lds_g[g] = a + p.db1[row];
      __syncthreads();
      if (tid < 2) {
        const int uu = w * 2 + tid;
        const float gi = lds_g[tid * 4 + 0];
        const float gf = lds_g[tid * 4 + 1];
        const float gg = lds_g[tid * 4 + 2];
        const float go = lds_g[tid * 4 + 3];
        const float c  = C1d[uu];
        const float c2 = sigmf(gf) * c + sigmf(gi) * tanhf(gg);
        C1d[uu] = c2;
        H1d[((t + 1) & 1) * 512 + uu] = sigmf(go) * tanhf(c2);
      }
    }
    grid_barrier(p, ++gen);
    // ---- D2: FC logits + per-WG argmax candidate ----
    {
      const int wave = tid >> 6, lane = tid & 63;
      const float* h1 = H1d + ((t + 1) & 1) * 512;
      const float4* hv = reinterpret_cast<const float4*>(h1) + lane * 2;
      const float4 hx = hv[0], hy = hv[1];
      const int base = w * 125;  // 32000 / 256
      float bv = -INFINITY; int bi = 0x7fffffff;
#pragma unroll 2
      for (int j = wave; j < 125; j += 4) {
        const int row = base + j;
        const float4* wr =
            reinterpret_cast<const float4*>(p.dfcW + (size_t)row * 512) + lane * 2;
        const float4 w0 = wr[0], w1 = wr[1];
        float a = w0.x * hx.x + w0.y * hx.y + w0.z * hx.z + w0.w * hx.w
                + w1.x * hy.x + w1.y * hy.y + w1.z * hy.z + w1.w * hy.w;
        a += __shfl_down(a, 32);
        a += __shfl_down(a, 16);
        a += __shfl_down(a, 8);
        a += __shfl_down(a, 4);
        a += __shfl_down(a, 2);
        a += __shfl_down(a, 1);
        if (lane == 0) {
          a += p.dfcb[row];
          p.out[(size_t)(t + 1) * kV + row] = a;
          if (a > bv) { bv = a; bi = row; }  // rows ascending: '>' keeps first
        }
      }
      if (lane == 0) { lds_rv[wave] = bv; lds_ri[wave] = bi; }
      __syncthreads();
      if (tid == 0) {
        float Bv = lds_rv[0]; int Bi = lds_ri[0];
#pragma unroll
        for (int k2 = 1; k2 < 4; ++k2) {
          if (lds_rv[k2] > Bv || (lds_rv[k2] == Bv && lds_ri[k2] < Bi)) {
            Bv = lds_rv[k2]; Bi = lds_ri[k2];
          }
        }
        candv[w] = Bv; candi[w] = Bi;
      }
    }
    grid_barrier(p, ++gen);
  }

  // zero output row 0 (P0 scratch in d_out, if used, is dead by now)
  {
    const int idx = w * NTHR + tid;
    if (idx < kV) p.out[idx] = 0.f;
  }
}

extern "C" void kernel_launch(void* const* d_in, const int* in_sizes, int n_in,
                              void* d_out, int out_size, void* d_ws, size_t ws_size,
                              hipStream_t stream) {
  (void)in_sizes; (void)n_in; (void)out_size;
  SeqParams P;
  P.x     = (const int*)d_in[0];
  P.y     = (const int*)d_in[1];
  P.emb   = (const float*)d_in[2];
  P.eWih0 = (const float*)d_in[3];
  P.eWhh0 = (const float*)d_in[4];
  P.eb0   = (const float*)d_in[5];
  P.eWih1 = (const float*)d_in[6];
  P.eWhh1 = (const float*)d_in[7];
  P.eb1   = (const float*)d_in[8];
  P.efcW  = (const float*)d_in[9];
  P.efcb  = (const float*)d_in[10];
  P.dWih0 = (const float*)d_in[11];
  P.dWhh0 = (const float*)d_in[12];
  P.db0   = (const float*)d_in[13];
  P.dWih1 = (const float*)d_in[14];
  P.dWhh1 = (const float*)d_in[15];
  P.db1   = (const float*)d_in[16];
  P.dfcW  = (const float*)d_in[17];
  P.dfcb  = (const float*)d_in[18];
  P.out   = (float*)d_out;

  char* ws = (char*)d_ws;
  P.arrive = (unsigned*)ws;                 // 256 slots * 128B
  P.go     = (unsigned*)(ws + 32768);
  P.st     = (float*)(ws + 32896);          // ~26.6KB of state
  const size_t p0_need = 65536ull + 2048ull * 1024ull * sizeof(float);
  // P0 staging: prefer ws; fall back to d_out (region dead before decoder
  // overwrites it; row 0 re-zeroed at kernel end).
  P.P0 = (ws_size >= p0_need) ? (float*)(ws + 65536) : (float*)d_out;

  // Reset barrier slots + go flag every call (poison-safe, replay-safe).
  hipMemsetAsync(d_ws, 0, 32896, stream);

  void* args[] = { &P };
  hipLaunchCooperativeKernel(reinterpret_cast<void*>(seq2seq_kernel),
                             dim3(NWG), dim3(NTHR), args, 0, stream);
}

// Round 2
// 12925.137 us; speedup vs baseline: 3.0501x; 3.0501x over previous
//
#include <hip/hip_runtime.h>
#include <cmath>

#define NWG 256
#define NTHR 1024

static constexpr int kV = 32000;
static constexpr int kS = 1024;
static constexpr int kT = 512;

struct SeqParams {
  const int* x; const int* y;
  const float* emb;
  const float* eWih0; const float* eWhh0; const float* eb0;
  const float* eWih1; const float* eWhh1; const float* eb1;
  const float* efcW;  const float* efcb;
  const float* dWih0; const float* dWhh0; const float* db0;
  const float* dWih1; const float* dWhh1; const float* db1;
  const float* dfcW;  const float* dfcb;
  float* out;
  float* P0;                 // [1024][2048] staging (ws or d_out fallback)
  float* st;                 // state area in ws
  unsigned long long* cand;  // [256] packed argmax candidates
  unsigned* arrive;          // 256 slots, 128B stride
  unsigned* go;              // 256 slots, 128B stride
};

__device__ __forceinline__ float sigmf(float v) { return 1.0f / (1.0f + expf(-v)); }

__device__ __forceinline__ float g_ld(const float* p_) {
  return __hip_atomic_load(p_, __ATOMIC_RELAXED, __HIP_MEMORY_SCOPE_AGENT);
}
__device__ __forceinline__ void g_st(float* p_, float v) {
  __hip_atomic_store(p_, v, __ATOMIC_RELAXED, __HIP_MEMORY_SCOPE_AGENT);
}
__device__ __forceinline__ unsigned long long g_ld64(const unsigned long long* p_) {
  return __hip_atomic_load(p_, __ATOMIC_RELAXED, __HIP_MEMORY_SCOPE_AGENT);
}
__device__ __forceinline__ void g_st64(unsigned long long* p_, unsigned long long v) {
  __hip_atomic_store(p_, v, __ATOMIC_RELAXED, __HIP_MEMORY_SCOPE_AGENT);
}

__device__ __forceinline__ float dot4(float4 a, float4 b) {
  return a.x * b.x + a.y * b.y + a.z * b.z + a.w * b.w;
}
__device__ __forceinline__ float wred(float a) {
  a += __shfl_down(a, 32);
  a += __shfl_down(a, 16);
  a += __shfl_down(a, 8);
  a += __shfl_down(a, 4);
  a += __shfl_down(a, 2);
  a += __shfl_down(a, 1);
  return a;
}

// Contention-free grid barrier. Entry __syncthreads drains every wave's
// vmcnt (compiler emits s_waitcnt vmcnt(0) before s_barrier), so all sc1
// data stores are LLC-visible before the arrive store. Every flag line has
// exactly one writer and one poller -> no hot-line serialization.
__device__ void grid_barrier(const SeqParams& p, unsigned gen) {
  __syncthreads();
  const int tid = threadIdx.x;
  if (blockIdx.x == 0) {
    if (tid > 0 && tid < 256) {
      while (__hip_atomic_load(&p.arrive[tid * 32], __ATOMIC_RELAXED,
                               __HIP_MEMORY_SCOPE_AGENT) < gen)
        __builtin_amdgcn_s_sleep(1);
    }
    __syncthreads();
    if (tid > 0 && tid < 256) {
      __hip_atomic_store(&p.go[tid * 32], gen, __ATOMIC_RELAXED,
                         __HIP_MEMORY_SCOPE_AGENT);
    }
  } else {
    if (tid == 0) {
      __hip_atomic_store(&p.arrive[blockIdx.x * 32], gen, __ATOMIC_RELAXED,
                         __HIP_MEMORY_SCOPE_AGENT);
      while (__hip_atomic_load(&p.go[blockIdx.x * 32], __ATOMIC_RELAXED,
                               __HIP_MEMORY_SCOPE_AGENT) < gen)
        __builtin_amdgcn_s_sleep(1);
    }
    __syncthreads();
  }
}

__global__ __launch_bounds__(NTHR) void seq2seq_kernel(SeqParams p) {
  __shared__ __align__(16) float lds_em[2048];  // 8KB, phase-0 only
  __shared__ __align__(16) float lds_h0[512];
  __shared__ __align__(16) float lds_h1[512];
  __shared__ float lds_g[16];
  __shared__ unsigned long long lds_pk[16];
  __shared__ float lds_tok;

  const int w = blockIdx.x;
  const int tid = threadIdx.x;
  const int wave = tid >> 6, lane = tid & 63;
  unsigned gen = 0;

  // state layout (floats) in ws
  float* H0e = p.st;                 // [2][512]
  float* H1e = p.st + 1024;          // [2][512]
  float* H0d = p.st + 2048;          // [2][512]
  float* H1d = p.st + 3072;          // [2][512]

  // ============ Phase 0: P0 = emb[x] @ Wih0^T + b0 ; zero enc h ============
  {
    if (w == 0 && tid < 512) { g_st(&H0e[tid], 0.f); g_st(&H1e[tid], 0.f); }
    const int t0  = (w & 127) * 8;          // 8 timesteps per WG
    const int row = (w >> 7) * 1024 + tid;  // 2 row-slices of 1024
    float4* emv = reinterpret_cast<float4*>(lds_em);
    if (tid < 512) {
      const int tl = tid >> 6, kq = tid & 63;
      const int tk = p.x[t0 + tl];
      emv[tid] = reinterpret_cast<const float4*>(p.emb)[(size_t)tk * 64 + kq];
    }
    __syncthreads();
    float acc[8];
    const float b = p.eb0[row];
#pragma unroll
    for (int t = 0; t < 8; ++t) acc[t] = b;
    for (int kc = 0; kc < 4; ++kc) {
      float4 wv[16];
      const float4* wr =
          reinterpret_cast<const float4*>(p.eWih0 + (size_t)row * 256) + kc * 16;
#pragma unroll
      for (int i = 0; i < 16; ++i) wv[i] = wr[i];
#pragma unroll
      for (int t = 0; t < 8; ++t) {
        const float4* ev =
            reinterpret_cast<const float4*>(lds_em + t * 256) + kc * 16;
        float a = acc[t];
#pragma unroll
        for (int i = 0; i < 16; ++i) a += dot4(wv[i], ev[i]);
        acc[t] = a;
      }
    }
#pragma unroll
    for (int t = 0; t < 8; ++t)
      g_st(&p.P0[(size_t)(t0 + t) * 2048 + row], acc[t]);
  }
  grid_barrier(p, ++gen);

  // ============ Encoder: pipelined L0(t=ph) || L1(t=ph-1) ==================
  float c0e = 0.f, c1e = 0.f;   // per-unit cell state, WG-private (registers)
  int row_l0 = 0;
  float pv_next = 0.f;
  if (w < 128) {
    row_l0 = (wave & 3) * 512 + w * 4 + (wave >> 2);
    if (lane == 0) pv_next = g_ld(&p.P0[row_l0]);  // prefetch P0[t=0]
  }

  for (int ph = 0; ph <= kS; ++ph) {
    if (w < 128) {
      if (ph < kS) {
        if (tid < 512) lds_h0[tid] = g_ld(&H0e[(ph & 1) * 512 + tid]);
        __syncthreads();
        const float pv = pv_next;
        if (lane == 0 && ph + 1 < kS)
          pv_next = g_ld(&p.P0[(size_t)(ph + 1) * 2048 + row_l0]);
        const float4* W4 =
            reinterpret_cast<const float4*>(p.eWhh0 + (size_t)row_l0 * 512);
        const float4* h4 = reinterpret_cast<const float4*>(lds_h0);
        float a = dot4(W4[lane * 2], h4[lane * 2]) +
                  dot4(W4[lane * 2 + 1], h4[lane * 2 + 1]);
        a = wred(a);
        if (lane == 0) lds_g[wave] = a + pv;  // pv includes b0
        __syncthreads();
        if (tid < 4) {
          const int u = w * 4 + tid;
          const float gi = lds_g[tid * 4 + 0];
          const float gf = lds_g[tid * 4 + 1];
          const float gg = lds_g[tid * 4 + 2];
          const float go = lds_g[tid * 4 + 3];
          const float c2 = sigmf(gf) * c0e + sigmf(gi) * tanhf(gg);
          c0e = c2;
          g_st(&H0e[((ph + 1) & 1) * 512 + u], sigmf(go) * tanhf(c2));
        }
      }
    } else {
      if (ph >= 1) {
        const int ww = w - 128;
        if (tid < 512) lds_h0[tid] = g_ld(&H0e[(ph & 1) * 512 + tid]);
        else lds_h1[tid - 512] = g_ld(&H1e[((ph - 1) & 1) * 512 + (tid - 512)]);
        __syncthreads();
        const int row = (wave & 3) * 512 + ww * 4 + (wave >> 2);
        const float4* Wa =
            reinterpret_cast<const float4*>(p.eWih1 + (size_t)row * 512);
        const float4* Wb =
            reinterpret_cast<const float4*>(p.eWhh1 + (size_t)row * 512);
        const float4* h4a = reinterpret_cast<const float4*>(lds_h0);
        const float4* h4b = reinterpret_cast<const float4*>(lds_h1);
        float a = (lane == 0) ? p.eb1[row] : 0.f;
        a += dot4(Wa[lane * 2], h4a[lane * 2]) +
             dot4(Wa[lane * 2 + 1], h4a[lane * 2 + 1]);
        a += dot4(Wb[lane * 2], h4b[lane * 2]) +
             dot4(Wb[lane * 2 + 1], h4b[lane * 2 + 1]);
        a = wred(a);
        if (lane == 0) lds_g[wave] = a;
        __syncthreads();
        if (tid < 4) {
          const int u = ww * 4 + tid;
          const float gi = lds_g[tid * 4 + 0];
          const float gf = lds_g[tid * 4 + 1];
          const float gg = lds_g[tid * 4 + 2];
          const float go = lds_g[tid * 4 + 3];
          const float c2 = sigmf(gf) * c1e + sigmf(gi) * tanhf(gg);
          c1e = c2;
          g_st(&H1e[(ph & 1) * 512 + u], sigmf(go) * tanhf(c2));
        }
      }
    }
    grid_barrier(p, ++gen);
  }

  // ============ z = relu(efcW @ h1_final + efcb); init decoder =============
  float c0d = 0.f, c1d = 0.f;
  {
    if (tid < 512) lds_h0[tid] = g_ld(&H1e[tid]);  // final h1 in buf 0
    __syncthreads();
    if (wave < 2) {
      const int u = w * 2 + wave;
      const float4* W4 =
          reinterpret_cast<const float4*>(p.efcW + (size_t)u * 512);
      const float4* h4 = reinterpret_cast<const float4*>(lds_h0);
      float a = dot4(W4[lane * 2], h4[lane * 2]) +
                dot4(W4[lane * 2 + 1], h4[lane * 2 + 1]);
      a = wred(a);
      if (lane == 0) lds_g[wave] = fmaxf(a + p.efcb[u], 0.f);
    }
    __syncthreads();
    if (tid < 2) {
      const int uu = w * 2 + tid;
      const float z = lds_g[tid];
      c0d = z; c1d = z;
      g_st(&H0d[uu], z);
      g_st(&H1d[uu], z);
    }
  }
  grid_barrier(p, ++gen);

  // ============ Decoder: 511 steps, 3 phases each ===========================
  for (int t = 0; t < kT - 1; ++t) {
    // ---- D0: (token reduce by wave 15) || Whh0 @ h0 dots ----
    {
      if (tid < 512) lds_h0[tid] = g_ld(&H0d[(t & 1) * 512 + tid]);
      if (wave == 15) {
        if (t == 0) {
          if (lane == 0) lds_tok = (float)p.y[0];
        } else {
          unsigned long long pk = 0;
#pragma unroll
          for (int k2 = 0; k2 < 4; ++k2) {
            const unsigned long long v = g_ld64(&p.cand[lane + k2 * 64]);
            if (v > pk) pk = v;
          }
#pragma unroll
          for (int off = 32; off >= 1; off >>= 1) {
            const unsigned long long o = __shfl_down(pk, off);
            if (o > pk) pk = o;
          }
          if (lane == 0)
            lds_tok = (float)(~(unsigned)(pk & 0xFFFFFFFFull));
        }
      }
      __syncthreads();
      if (wave < 8) {
        const int row = (wave & 3) * 512 + w * 2 + (wave >> 2);
        const float4* W4 =
            reinterpret_cast<const float4*>(p.dWhh0 + (size_t)row * 512);
        const float4* h4 = reinterpret_cast<const float4*>(lds_h0);
        float a = dot4(W4[lane * 2], h4[lane * 2]) +
                  dot4(W4[lane * 2 + 1], h4[lane * 2 + 1]);
        a = wred(a);
        if (lane == 0) lds_g[wave] = a;
      }
      __syncthreads();
      if (tid < 2) {
        const float tok = lds_tok;
        const int uu = w * 2 + tid;
        float gv[4];
#pragma unroll
        for (int g = 0; g < 4; ++g) {
          const int rg = g * 512 + uu;
          gv[g] = lds_g[tid * 4 + g] + p.dWih0[rg] * tok + p.db0[rg];
        }
        const float c2 = sigmf(gv[1]) * c0d + sigmf(gv[0]) * tanhf(gv[2]);
        c0d = c2;
        g_st(&H0d[((t + 1) & 1) * 512 + uu], sigmf(gv[3]) * tanhf(c2));
      }
    }
    grid_barrier(p, ++gen);
    // ---- D1: Wih1 @ h0_new + Whh1 @ h1_old ----
    {
      if (tid < 512) lds_h0[tid] = g_ld(&H0d[((t + 1) & 1) * 512 + tid]);
      else lds_h1[tid - 512] = g_ld(&H1d[(t & 1) * 512 + (tid - 512)]);
      __syncthreads();
      if (wave < 8) {
        const int row = (wave & 3) * 512 + w * 2 + (wave >> 2);
        const float4* Wa =
            reinterpret_cast<const float4*>(p.dWih1 + (size_t)row * 512);
        const float4* Wb =
            reinterpret_cast<const float4*>(p.dWhh1 + (size_t)row * 512);
        const float4* h4a = reinterpret_cast<const float4*>(lds_h0);
        const float4* h4b = reinterpret_cast<const float4*>(lds_h1);
        float a = (lane == 0) ? p.db1[row] : 0.f;
        a += dot4(Wa[lane * 2], h4a[lane * 2]) +
             dot4(Wa[lane * 2 + 1], h4a[lane * 2 + 1]);
        a += dot4(Wb[lane * 2], h4b[lane * 2]) +
             dot4(Wb[lane * 2 + 1], h4b[lane * 2 + 1]);
        a = wred(a);
        if (lane == 0) lds_g[wave] = a;
      }
      __syncthreads();
      if (tid < 2) {
        const int uu = w * 2 + tid;
        const float gi = lds_g[tid * 4 + 0];
        const float gf = lds_g[tid * 4 + 1];
        const float gg = lds_g[tid * 4 + 2];
        const float go = lds_g[tid * 4 + 3];
        const float c2 = sigmf(gf) * c1d + sigmf(gi) * tanhf(gg);
        c1d = c2;
        g_st(&H1d[((t + 1) & 1) * 512 + uu], sigmf(go) * tanhf(c2));
      }
    }
    grid_barrier(p, ++gen);
    // ---- FC: logits + packed argmax candidate ----
    {
      if (tid < 512) lds_h0[tid] = g_ld(&H1d[((t + 1) & 1) * 512 + tid]);
      __syncthreads();
      const float4* h4 = reinterpret_cast<const float4*>(lds_h0);
      const float4 ha = h4[lane * 2], hb = h4[lane * 2 + 1];
      const int base = w * 125;
      unsigned long long best = 0;
#pragma unroll 2
      for (int j = wave; j < 125; j += 16) {
        const int row = base + j;
        const float4* wr =
            reinterpret_cast<const float4*>(p.dfcW + (size_t)row * 512) + lane * 2;
        float a = (lane == 0) ? p.dfcb[row] : 0.f;
        a += dot4(wr[0], ha) + dot4(wr[1], hb);
        a = wred(a);
        if (lane == 0) {
          p.out[(size_t)(t + 1) * kV + row] = a;
          const unsigned u = __float_as_uint(a);
          const unsigned key = u ^ (unsigned)(((int)u >> 31) | 0x80000000);
          const unsigned long long pk2 =
              ((unsigned long long)key << 32) | (unsigned)(~row);
          if (pk2 > best) best = pk2;
        }
      }
      if (lane == 0) lds_pk[wave] = best;
      __syncthreads();
      if (tid == 0) {
        unsigned long long b2 = lds_pk[0];
#pragma unroll
        for (int k2 = 1; k2 < 16; ++k2)
          if (lds_pk[k2] > b2) b2 = lds_pk[k2];
        g_st64(&p.cand[w], b2);
      }
    }
    grid_barrier(p, ++gen);
  }

  // zero output row 0 (P0 scratch in d_out, if used, is dead by now)
  {
    const int idx = w * NTHR + tid;
    if (idx < kV) p.out[idx] = 0.f;
  }
}

extern "C" void kernel_launch(void* const* d_in, const int* in_sizes, int n_in,
                              void* d_out, int out_size, void* d_ws, size_t ws_size,
                              hipStream_t stream) {
  (void)in_sizes; (void)n_in; (void)out_size;
  SeqParams P;
  P.x     = (const int*)d_in[0];
  P.y     = (const int*)d_in[1];
  P.emb   = (const float*)d_in[2];
  P.eWih0 = (const float*)d_in[3];
  P.eWhh0 = (const float*)d_in[4];
  P.eb0   = (const float*)d_in[5];
  P.eWih1 = (const float*)d_in[6];
  P.eWhh1 = (const float*)d_in[7];
  P.eb1   = (const float*)d_in[8];
  P.efcW  = (const float*)d_in[9];
  P.efcb  = (const float*)d_in[10];
  P.dWih0 = (const float*)d_in[11];
  P.dWhh0 = (const float*)d_in[12];
  P.db0   = (const float*)d_in[13];
  P.dWih1 = (const float*)d_in[14];
  P.dWhh1 = (const float*)d_in[15];
  P.db1   = (const float*)d_in[16];
  P.dfcW  = (const float*)d_in[17];
  P.dfcb  = (const float*)d_in[18];
  P.out   = (float*)d_out;

  char* ws = (char*)d_ws;
  P.arrive = (unsigned*)ws;                       // 256 * 128B = 32KB
  P.go     = (unsigned*)(ws + 32768);             // 256 * 128B = 32KB
  P.st     = (float*)(ws + 65536);                // 4096 floats = 16KB
  P.cand   = (unsigned long long*)(ws + 65536 + 16384);  // 2KB
  const size_t p0_off  = 65536 + 16384 + 2048;
  const size_t p0_need = p0_off + 2048ull * 1024ull * sizeof(float);
  // P0 staging: prefer ws; fall back to d_out (region dead before decoder
  // overwrites it; row 0 re-zeroed at kernel end).
  P.P0 = (ws_size >= p0_need) ? (float*)(ws + p0_off) : (float*)d_out;

  // Reset barrier generations every call (poison-safe, replay-safe).
  hipMemsetAsync(d_ws, 0, 65536, stream);

  void* args[] = { &P };
  hipLaunchCooperativeKernel(reinterpret_cast<void*>(seq2seq_kernel),
                             dim3(NWG), dim3(NTHR), args, 0, stream);
}